// Round 5
// baseline (759.367 us; speedup 1.0000x reference)
//
#include <hip/hip_runtime.h>

// Circular conv1d: x (B=64, C_in=8, L=65536) fp32, W (8,8,4), b (8,).
// Memory-bound, floor ~32us (68MB HBM fetch after L3 absorption + 131MB
// write at 6.3 TB/s). R2/R4 plateaued at 50us: per-block {load, barrier,
// compute, store} phases expose HBM latency; TLP alone -> 4 TB/s.
// This version: persistent grid, register double-buffer, NO barriers in
// the main loop. Each thread pipelines 8 half-channel units across 4
// tiles; 8 float4 loads always in flight under 512 FMAs of compute.
#define BATCH 64
#define CIN 8
#define COUT 8
#define LEN 65536
#define FS 4
#define TPB 16384                 // thread-tiles (4 positions) per batch row
#define NBLOCKS 1024
#define TOTAL_THREADS (NBLOCKS * 256)
#define ITERS 4                   // BATCH*TPB / TOTAL_THREADS

typedef float floatx4 __attribute__((ext_vector_type(4)));

__device__ __forceinline__ void load_half(const float* __restrict__ x,
                                          int T, int H, floatx4 (&buf)[4][2])
{
    const int b  = T >> 14;             // T / TPB
    const int l0 = (T & (TPB - 1)) << 2;
    const float* xb = x + ((size_t)b << 19);   // b * CIN*LEN
    if (l0 + 8 <= LEN) {
#pragma unroll
        for (int c = 0; c < 4; ++c) {
            const float* xc = xb + ((size_t)(H * 4 + c) << 16) + l0;
            buf[c][0] = *reinterpret_cast<const floatx4*>(xc);
            buf[c][1] = *reinterpret_cast<const floatx4*>(xc + 4);
        }
    } else {
        // circular wrap: only tile l0 == LEN-4 (1 thread-tile in 16384)
#pragma unroll
        for (int c = 0; c < 4; ++c) {
            const float* xc = xb + ((size_t)(H * 4 + c) << 16);
            float t[8];
#pragma unroll
            for (int j = 0; j < 8; ++j) t[j] = xc[(l0 + j) & (LEN - 1)];
            buf[c][0] = floatx4{t[0], t[1], t[2], t[3]};
            buf[c][1] = floatx4{t[4], t[5], t[6], t[7]};
        }
    }
}

__device__ __forceinline__ void compute_half(const float* sW,
                                             const floatx4 (&buf)[4][2], int H,
                                             float (&acc)[COUT][4])
{
#pragma unroll
    for (int c = 0; c < 4; ++c) {
        const int ci = H * 4 + c;
        float xv[8];
        xv[0] = buf[c][0].x; xv[1] = buf[c][0].y; xv[2] = buf[c][0].z; xv[3] = buf[c][0].w;
        xv[4] = buf[c][1].x; xv[5] = buf[c][1].y; xv[6] = buf[c][1].z; xv[7] = buf[c][1].w;
#pragma unroll
        for (int co = 0; co < COUT; ++co) {
            // 4 taps as one ds_read_b128, wave-uniform broadcast
            const floatx4 wv = *reinterpret_cast<const floatx4*>(&sW[(co * CIN + ci) * FS]);
#pragma unroll
            for (int p = 0; p < 4; ++p) {
                acc[co][p] += wv.x * xv[p + 0];
                acc[co][p] += wv.y * xv[p + 1];
                acc[co][p] += wv.z * xv[p + 2];
                acc[co][p] += wv.w * xv[p + 3];
            }
        }
    }
}

__device__ __forceinline__ void store_tile(float* __restrict__ out, int T,
                                           const float (&acc)[COUT][4])
{
    const int b  = T >> 14;
    const int l0 = (T & (TPB - 1)) << 2;
    float* ob = out + ((size_t)b << 19) + l0;   // b * COUT*LEN
#pragma unroll
    for (int co = 0; co < COUT; ++co) {
        floatx4 v = {acc[co][0], acc[co][1], acc[co][2], acc[co][3]};
        __builtin_nontemporal_store(v, reinterpret_cast<floatx4*>(ob + ((size_t)co << 16)));
    }
}

__global__ __launch_bounds__(256, 4) void conv_pbc_kernel(
    const float* __restrict__ x,
    const float* __restrict__ W,
    const float* __restrict__ bias,
    float* __restrict__ out)
{
    __shared__ float sW[COUT * CIN * FS];   // 256 floats
    __shared__ float sB[COUT];

    const int tid = threadIdx.x;
    sW[tid] = W[tid];                       // 256 == COUT*CIN*FS
    if (tid < COUT) sB[tid] = bias[tid];
    __syncthreads();

    float bias_r[COUT];
#pragma unroll
    for (int co = 0; co < COUT; ++co) bias_r[co] = sB[co];

    const int g = blockIdx.x * 256 + tid;

    floatx4 bufA[4][2], bufB[4][2];
    float acc[COUT][4];

    // prologue: half 0 of first tile in flight
    load_half(x, g, 0, bufA);

#pragma unroll
    for (int i = 0; i < ITERS; ++i) {
        const int T = g + i * TOTAL_THREADS;
        // prefetch half 1 of this tile, then compute half 0 (loads in flight)
        load_half(x, T, 1, bufB);
#pragma unroll
        for (int co = 0; co < COUT; ++co) {
            acc[co][0] = bias_r[co]; acc[co][1] = bias_r[co];
            acc[co][2] = bias_r[co]; acc[co][3] = bias_r[co];
        }
        compute_half(sW, bufA, 0, acc);
        // prefetch half 0 of next tile, then compute half 1
        if (i + 1 < ITERS) load_half(x, g + (i + 1) * TOTAL_THREADS, 0, bufA);
        compute_half(sW, bufB, 1, acc);
        store_tile(out, T, acc);
    }
}

extern "C" void kernel_launch(void* const* d_in, const int* in_sizes, int n_in,
                              void* d_out, int out_size, void* d_ws, size_t ws_size,
                              hipStream_t stream) {
    const float* x    = (const float*)d_in[0];
    const float* W    = (const float*)d_in[1];
    const float* bias = (const float*)d_in[2];
    float* out = (float*)d_out;

    conv_pbc_kernel<<<dim3(NBLOCKS), dim3(256), 0, stream>>>(x, W, bias, out);
}

// Round 6
// 350.944 us; speedup vs baseline: 2.1638x; 2.1638x over previous
//
#include <hip/hip_runtime.h>

// Circular conv1d: x (B=64, C_in=8, L=65536) fp32, W (8,8,4), b (8,).
// Memory-bound; min traffic ~200MB (68MB fetch after L3 + 134MB write)
// -> ~32us floor. R2/R4 sit at 50us: compiler doesn't pipeline global
// loads across iterations, so each wave alternates {loads, drain, FMA}.
// This version: software pipeline in ONE function body (R5's version
// passed register arrays by reference to helpers -> scratch, 1.2GB of
// spill traffic each way). All arrays here are literal-indexed after
// full unroll -> register-promoted (the R1/R2-proven pattern).
#define BATCH 64
#define CIN 8
#define COUT 8
#define LEN 65536
#define FS 4
#define NBLOCKS 1024
#define NTHREADS 256
#define TOTAL (NBLOCKS * NTHREADS)          // 262144 threads
#define TILES_TOTAL (BATCH * (LEN / 4))     // 1048576 thread-tiles (4 pos)
#define ITERS (TILES_TOTAL / TOTAL)         // 4, exact

typedef float floatx4 __attribute__((ext_vector_type(4)));

__global__ __launch_bounds__(256, 4) void conv_pbc_kernel(
    const float* __restrict__ x,
    const float* __restrict__ W,
    const float* __restrict__ bias,
    float* __restrict__ out)
{
    __shared__ floatx4 sWv[COUT * CIN];   // (co,ci) -> 4 taps as one float4
    __shared__ float sB[COUT];

    const int tid = threadIdx.x;
    if (tid < COUT * CIN) sWv[tid] = *reinterpret_cast<const floatx4*>(W + tid * FS);
    if (tid < COUT)       sB[tid] = bias[tid];
    __syncthreads();

    float bR[COUT];
#pragma unroll
    for (int co = 0; co < COUT; ++co) bR[co] = sB[co];

    const int g = blockIdx.x * NTHREADS + tid;

    // current tile coords. Tile T -> batch b = T>>14, l0 = (T&16383)*4.
    int b  = g >> 14;
    int l0 = (g & 16383) << 2;
    const float* pb = x + ((size_t)b << 19);     // b * CIN*LEN
    int o0 = l0;
    int o1 = (l0 + 4) & (LEN - 1);               // branch-free circular wrap:
                                                 // a float4 never straddles L
    floatx4 buf[2][4];                           // [parity][2ch x 2 float4]
    float acc[COUT][4];

    // LOADQ: issue 4 independent float4 loads for channels CI0, CI0+1
#define LOADQ(P, PB, O0, O1, CI0)                                            \
    do {                                                                     \
        const float* _c0 = (PB) + ((size_t)(CI0) << 16);                     \
        const float* _c1 = (PB) + ((size_t)((CI0) + 1) << 16);               \
        buf[P][0] = *reinterpret_cast<const floatx4*>(_c0 + (O0));           \
        buf[P][1] = *reinterpret_cast<const floatx4*>(_c0 + (O1));           \
        buf[P][2] = *reinterpret_cast<const floatx4*>(_c1 + (O0));           \
        buf[P][3] = *reinterpret_cast<const floatx4*>(_c1 + (O1));           \
    } while (0)

    // COMPQ: 256 FMAs over channels CI0, CI0+1 from buffer parity P
#define COMPQ(P, CI0)                                                        \
    do {                                                                     \
        const float xv0[8] = {buf[P][0].x, buf[P][0].y, buf[P][0].z,         \
                              buf[P][0].w, buf[P][1].x, buf[P][1].y,         \
                              buf[P][1].z, buf[P][1].w};                     \
        const float xv1[8] = {buf[P][2].x, buf[P][2].y, buf[P][2].z,         \
                              buf[P][2].w, buf[P][3].x, buf[P][3].y,         \
                              buf[P][3].z, buf[P][3].w};                     \
        _Pragma("unroll")                                                    \
        for (int co = 0; co < COUT; ++co) {                                  \
            const floatx4 w0 = sWv[co * CIN + (CI0)];                        \
            const floatx4 w1 = sWv[co * CIN + (CI0) + 1];                    \
            _Pragma("unroll")                                                \
            for (int p = 0; p < 4; ++p) {                                    \
                acc[co][p] += w0.x * xv0[p]     + w0.y * xv0[p + 1]          \
                            + w0.z * xv0[p + 2] + w0.w * xv0[p + 3];         \
                acc[co][p] += w1.x * xv1[p]     + w1.y * xv1[p + 1]          \
                            + w1.z * xv1[p + 2] + w1.w * xv1[p + 3];         \
            }                                                                \
        }                                                                    \
    } while (0)

    LOADQ(0, pb, o0, o1, 0);   // prologue: Q0 of tile 0 in flight

#pragma unroll
    for (int i = 0; i < ITERS; ++i) {
#pragma unroll
        for (int co = 0; co < COUT; ++co) {
            acc[co][0] = bR[co]; acc[co][1] = bR[co];
            acc[co][2] = bR[co]; acc[co][3] = bR[co];
        }

        // next-tile coords (for the cross-tile Q0 prefetch)
        const int T2  = g + (i + 1) * TOTAL;
        const int b2  = T2 >> 14;
        const int l02 = (T2 & 16383) << 2;
        const float* pb2 = x + ((size_t)b2 << 19);
        const int o02 = l02;
        const int o12 = (l02 + 4) & (LEN - 1);

        // steady state: 4 loads always in flight under each 256-FMA block
        LOADQ(1, pb, o0, o1, 2);        // Q1 in flight
        COMPQ(0, 0);                    // compute Q0
        LOADQ(0, pb, o0, o1, 4);        // Q2 in flight
        COMPQ(1, 2);                    // compute Q1
        LOADQ(1, pb, o0, o1, 6);        // Q3 in flight
        COMPQ(0, 4);                    // compute Q2
        if (i + 1 < ITERS)
            LOADQ(0, pb2, o02, o12, 0); // next tile's Q0 in flight
        COMPQ(1, 6);                    // compute Q3

        // store tile i (nontemporal: out is never re-read)
        float* ob = out + ((size_t)b << 19) + l0;
#pragma unroll
        for (int co = 0; co < COUT; ++co) {
            const floatx4 v = {acc[co][0], acc[co][1], acc[co][2], acc[co][3]};
            __builtin_nontemporal_store(v, reinterpret_cast<floatx4*>(ob + ((size_t)co << 16)));
        }

        b = b2; l0 = l02; pb = pb2; o0 = o02; o1 = o12;
    }
#undef LOADQ
#undef COMPQ
}

extern "C" void kernel_launch(void* const* d_in, const int* in_sizes, int n_in,
                              void* d_out, int out_size, void* d_ws, size_t ws_size,
                              hipStream_t stream) {
    const float* x    = (const float*)d_in[0];
    const float* W    = (const float*)d_in[1];
    const float* bias = (const float*)d_in[2];
    float* out = (float*)d_out;

    conv_pbc_kernel<<<dim3(NBLOCKS), dim3(NTHREADS), 0, stream>>>(x, W, bias, out);
}